// Round 4
// baseline (210.473 us; speedup 1.0000x reference)
//
#include <hip/hip_runtime.h>

#define BB 8
#define CC 8
#define HH 512
#define WW 512
#define HWSZ (HH * WW)
#define CHW (CC * HWSZ)

typedef float v4 __attribute__((ext_vector_type(4)));

#define LOG2_CLAMP -144.26950409f   // -100 / ln2

__device__ __forceinline__ float sigf(float x) {
    return __builtin_amdgcn_rcpf(1.0f + __expf(-x));
}

// Stage 14 rows (ch0..7 @ h, ch5..7 @ hm, ch0..2 @ hp) into LDS.
// 512 threads: 128 threads x dwordx4 per row, 4 rows per j-step.
__device__ __forceinline__ void stage_rows(const float* __restrict__ base,
                                           float* __restrict__ lds,
                                           int h, int hm, int hp,
                                           int rgrp, int col4)
{
#pragma unroll
    for (int j = 0; j < 4; ++j) {
        int row = j * 4 + rgrp;           // wave-uniform (rgrp = t>>7)
        if (row < 14) {
            int ch, grow;
            if (row < 8)       { ch = row;      grow = h;  }
            else if (row < 11) { ch = row - 3;  grow = hm; }   // 8,9,10 -> ch5,6,7
            else               { ch = row - 11; grow = hp; }   // 11,12,13 -> ch0,1,2
            v4 d = *(const v4* __restrict__)(base + ch * HWSZ + grow * WW + col4);
            *(v4*)(lds + row * WW + col4) = d;
        }
    }
}

// One branch from LDS. Votes: v[k] = sig(center ch k) * sig(neighbor ch 7-k, shifted).
template <bool NEED_MIN>
__device__ __forceinline__ void eval_lds(const float* __restrict__ L, int w,
                                         float mh0, float mh1,
                                         const float* __restrict__ cv,
                                         float& glo, float& vmin,
                                         float& Lbic, float& Lcon)
{
    const int wl = (w > 0) ? w - 1 : 0;
    const int wr = (w < WW - 1) ? w + 1 : WW - 1;
    const float mw0 = (w > 0) ? 1.0f : 0.0f;
    const float mw1 = (w < WW - 1) ? 1.0f : 0.0f;

    float s[8];
#pragma unroll
    for (int c = 0; c < 8; ++c) s[c] = sigf(L[c * WW + w]);

    float n[8];
    n[0] = sigf(L[10 * WW + wl]) * (mh0 * mw0);   // c7 @ h-1, w-1
    n[1] = sigf(L[ 9 * WW + w ]) *  mh0;          // c6 @ h-1, w
    n[2] = sigf(L[ 8 * WW + wr]) * (mh0 * mw1);   // c5 @ h-1, w+1
    n[3] = sigf(L[ 4 * WW + wl]) *  mw0;          // c4 @ h,   w-1
    n[4] = sigf(L[ 3 * WW + wr]) *  mw1;          // c3 @ h,   w+1
    n[5] = sigf(L[13 * WW + wl]) * (mh1 * mw0);   // c2 @ h+1, w-1
    n[6] = sigf(L[12 * WW + w ]) *  mh1;          // c1 @ h+1, w
    n[7] = sigf(L[11 * WW + wr]) * (mh1 * mw1);   // c0 @ h+1, w+1

    float pb0 = 1.f, pb1 = 1.f, pc = 1.f, vsum = 0.f;
    if (NEED_MIN) vmin = 1e30f;
#pragma unroll
    for (int k = 0; k < 8; ++k) {
        float v = s[k] * n[k];
        vsum += v;
        if (NEED_MIN) vmin = fminf(vmin, v);
        float t  = cv[k];
        float av = (t > 0.5f) ? v    : 1.0f - v;
        float as = (t > 0.5f) ? s[k] : 1.0f - s[k];
        if (k < 4) pb0 *= av; else pb1 *= av;
        pc *= as;
    }
    glo  = vsum * 0.125f;
    Lbic = fmaxf(__log2f(pb0), LOG2_CLAMP) + fmaxf(__log2f(pb1), LOG2_CLAMP);
    Lcon = fmaxf(__log2f(pc), LOG2_CLAMP);
}

__global__ __launch_bounds__(512, 8) void bicon_loss_kernel(
    const float* __restrict__ atts, const float* __restrict__ dets,
    const float* __restrict__ target, const float* __restrict__ con,
    float* __restrict__ out)
{
    __shared__ float L[14 * WW];     // 28 KB
    __shared__ float wsum[8];

    const int t   = threadIdx.x;     // = w
    const int row = blockIdx.x;      // b*H + h
    const int h   = row & (HH - 1);
    const int b   = row >> 9;
    const int w   = t;

    const int   hm  = (h > 0)      ? h - 1 : 0;
    const int   hp  = (h < HH - 1) ? h + 1 : HH - 1;
    const float mh0 = (h > 0)      ? 1.0f : 0.0f;
    const float mh1 = (h < HH - 1) ? 1.0f : 0.0f;

    const float* __restrict__ ab = atts + b * CHW;
    const float* __restrict__ db = dets + b * CHW;

    // con/target: coalesced, issued early so they fly during staging
    const float* __restrict__ cb = con + b * CHW + h * WW + w;
    float cv[8];
#pragma unroll
    for (int c = 0; c < 8; ++c) cv[c] = cb[c * HWSZ];
    const float tt = target[b * HWSZ + h * WW + w];

    const int rgrp = t >> 7;
    const int col4 = (t & 127) << 2;

    // phase A: atts
    stage_rows(ab, L, h, hm, hp, rgrp, col4);
    __syncthreads();
    float glo1, dum, Lb1, Lc1;
    eval_lds<false>(L, w, mh0, mh1, cv, glo1, dum, Lb1, Lc1);
    __syncthreads();                 // WAR: all reads done before overwrite

    // phase B: dets
    stage_rows(db, L, h, hm, hp, rgrp, col4);
    __syncthreads();
    float glo2, vmin2, Lb2, Lc2;
    eval_lds<true>(L, w, mh0, mh1, cv, glo2, vmin2, Lb2, Lc2);

    float csum = 0.f;
#pragma unroll
    for (int c = 0; c < 8; ++c) csum += cv[c];
    const float edge = (csum < 8.0f && csum > 0.0f) ? 1.0f : 0.0f;

    const float dec = (edge > 0.5f) ? (1.0f - vmin2) : glo2;
    const float a   = (tt > 0.5f) ? glo1 : 1.0f - glo1;
    const float bs  = (tt > 0.5f) ? dec  : 1.0f - dec;
    const float Lp  = fmaxf(__log2f(a * bs), LOG2_CLAMP);

    const float wbic = 0.2f / (float)(BB * CC * HWSZ);
    const float wcon = 0.8f / (float)(BB * CC * HWSZ);
    const float wpix = 1.0f / (float)(BB * HWSZ);
    const float ln2  = 0.69314718056f;

    float local = -(wbic * (Lb1 + Lb2) + wcon * (Lc1 + Lc2) + wpix * Lp) * ln2;

    // wave-64 reduce, then 8-wave block reduce, one atomic per block
#pragma unroll
    for (int off = 32; off > 0; off >>= 1)
        local += __shfl_down(local, off, 64);

    const int lane = t & 63;
    const int wid  = t >> 6;
    if (lane == 0) wsum[wid] = local;
    __syncthreads();
    if (t == 0) {
        float s = 0.f;
#pragma unroll
        for (int i = 0; i < 8; ++i) s += wsum[i];
        atomicAdd(out, s);
    }
}

extern "C" void kernel_launch(void* const* d_in, const int* in_sizes, int n_in,
                              void* d_out, int out_size, void* d_ws, size_t ws_size,
                              hipStream_t stream) {
    const float* atts   = (const float*)d_in[0];
    const float* dets   = (const float*)d_in[1];
    const float* target = (const float*)d_in[2];
    const float* con    = (const float*)d_in[3];
    float* out = (float*)d_out;

    hipMemsetAsync(out, 0, sizeof(float), stream);

    bicon_loss_kernel<<<BB * HH, 512, 0, stream>>>(atts, dets, target, con, out);
}

// Round 5
// 206.033 us; speedup vs baseline: 1.0216x; 1.0216x over previous
//
#include <hip/hip_runtime.h>

#define BB 8
#define CC 8
#define HH 512
#define WW 512
#define HWSZ (HH * WW)
#define CHW (CC * HWSZ)

typedef float v4 __attribute__((ext_vector_type(4)));

#define LOG2_CLAMP -144.26950409f   // -100 / ln2

__device__ __forceinline__ float sigf(float x) {
    return __builtin_amdgcn_rcpf(1.0f + __expf(-x));
}

// One branch. Lb = 8 shared LDS rows for this branch:
//   row0 ch3@h, row1 ch4@h, row2 ch5@hm, row3 ch6@hm, row4 ch7@hm,
//   row5 ch0@hp, row6 ch1@hp, row7 ch2@hp
// craw = raw center values ch0..7 (registers). Vote k: center ch k, neighbor ch 7-k.
template <bool NEED_MIN>
__device__ __forceinline__ void eval_branch(
    const float* __restrict__ Lb, const float* __restrict__ craw,
    int w, int wl, int wr, float mh0, float mh1, float mw0, float mw1,
    const float* __restrict__ cv,
    float& glo, float& vmin, float& Lbic, float& Lcon)
{
    float s[8];
#pragma unroll
    for (int c = 0; c < 8; ++c) s[c] = sigf(craw[c]);

    float n[8];
    n[0] = sigf(Lb[4 * WW + wl]) * (mh0 * mw0);   // ch7 @ h-1, w-1
    n[1] = sigf(Lb[3 * WW + w ]) *  mh0;          // ch6 @ h-1, w
    n[2] = sigf(Lb[2 * WW + wr]) * (mh0 * mw1);   // ch5 @ h-1, w+1
    n[3] = sigf(Lb[1 * WW + wl]) *  mw0;          // ch4 @ h,   w-1
    n[4] = sigf(Lb[0 * WW + wr]) *  mw1;          // ch3 @ h,   w+1
    n[5] = sigf(Lb[7 * WW + wl]) * (mh1 * mw0);   // ch2 @ h+1, w-1
    n[6] = sigf(Lb[6 * WW + w ]) *  mh1;          // ch1 @ h+1, w
    n[7] = sigf(Lb[5 * WW + wr]) * (mh1 * mw1);   // ch0 @ h+1, w+1

    float pb0 = 1.f, pb1 = 1.f, pc = 1.f, vsum = 0.f;
    if (NEED_MIN) vmin = 1e30f;
#pragma unroll
    for (int k = 0; k < 8; ++k) {
        float v = s[k] * n[k];
        vsum += v;
        if (NEED_MIN) vmin = fminf(vmin, v);
        float t  = cv[k];
        float av = (t > 0.5f) ? v    : 1.0f - v;
        float as = (t > 0.5f) ? s[k] : 1.0f - s[k];
        if (k < 4) pb0 *= av; else pb1 *= av;
        pc *= as;
    }
    glo  = vsum * 0.125f;
    Lbic = fmaxf(__log2f(pb0), LOG2_CLAMP) + fmaxf(__log2f(pb1), LOG2_CLAMP);
    Lcon = fmaxf(__log2f(pc), LOG2_CLAMP);
}

__global__ __launch_bounds__(512, 8) void bicon_loss_kernel(
    const float* __restrict__ atts, const float* __restrict__ dets,
    const float* __restrict__ target, const float* __restrict__ con,
    float* __restrict__ out)
{
    __shared__ float L[16 * WW];     // 32 KB: rows 0-7 atts, 8-15 dets
    __shared__ float wsum[8];

    const int t   = threadIdx.x;     // = w
    const int row = blockIdx.x;      // b*H + h
    const int h   = row & (HH - 1);
    const int b   = row >> 9;
    const int w   = t;

    const int   hm  = (h > 0)      ? h - 1 : 0;
    const int   hp  = (h < HH - 1) ? h + 1 : HH - 1;
    const float mh0 = (h > 0)      ? 1.0f : 0.0f;
    const float mh1 = (h < HH - 1) ? 1.0f : 0.0f;
    const int   wl  = (w > 0)      ? w - 1 : 0;
    const int   wr  = (w < WW - 1) ? w + 1 : WW - 1;
    const float mw0 = (w > 0)      ? 1.0f : 0.0f;
    const float mw1 = (w < WW - 1) ? 1.0f : 0.0f;

    const float* __restrict__ ab = atts + b * CHW;
    const float* __restrict__ db = dets + b * CHW;
    const int offC = h * WW + w;

    // ---- staging loads (the ONLY loads the barrier waits on) ----
    // 16 shared rows x 512 floats = 2048 dwordx4 chunks; 4 per thread.
    // chunk r = rgrp + 4*j; rr=r&7: ch = rr<5 ? rr+3 : rr-5 ;
    // grow = rr<2 ? h : (rr<5 ? hm : hp); branch = (j<2) ? atts : dets.
    const int rgrp = t >> 7;                  // 0..3, wave-uniform
    const int col4 = (t & 127) << 2;

    v4 stg[4];
#pragma unroll
    for (int j = 0; j < 4; ++j) {
        const int rr = rgrp + 4 * (j & 1);    // 0..7
        const int ch   = (rr < 5) ? rr + 3 : rr - 5;
        const int grow = (rr < 2) ? h : ((rr < 5) ? hm : hp);
        const float* base = (j < 2) ? ab : db;
        stg[j] = *(const v4* __restrict__)(base + ch * HWSZ + grow * WW + col4);
    }

    // ---- per-thread loads: independent of the barrier, drain during compute ----
    float cv[8];
#pragma unroll
    for (int c = 0; c < 8; ++c) cv[c] = con[b * CHW + c * HWSZ + offC];
    const float tt = target[b * HWSZ + offC];
    float ar[8], dr[8];
#pragma unroll
    for (int c = 0; c < 8; ++c) ar[c] = ab[c * HWSZ + offC];
#pragma unroll
    for (int c = 0; c < 8; ++c) dr[c] = db[c * HWSZ + offC];

    // ---- LDS write + single barrier ----
#pragma unroll
    for (int j = 0; j < 4; ++j) {
        const int r = rgrp + 4 * (j & 1) + ((j < 2) ? 0 : 8);
        *(v4*)(L + r * WW + col4) = stg[j];
    }
    __syncthreads();

    float glo1, glo2, vmin2, dum, Lb1, Lc1, Lb2, Lc2;
    eval_branch<false>(L,           ar, w, wl, wr, mh0, mh1, mw0, mw1, cv,
                       glo1, dum, Lb1, Lc1);
    eval_branch<true >(L + 8 * WW,  dr, w, wl, wr, mh0, mh1, mw0, mw1, cv,
                       glo2, vmin2, Lb2, Lc2);

    float csum = 0.f;
#pragma unroll
    for (int c = 0; c < 8; ++c) csum += cv[c];
    const float edge = (csum < 8.0f && csum > 0.0f) ? 1.0f : 0.0f;

    const float dec = (edge > 0.5f) ? (1.0f - vmin2) : glo2;
    const float a   = (tt > 0.5f) ? glo1 : 1.0f - glo1;
    const float bs  = (tt > 0.5f) ? dec  : 1.0f - dec;
    const float Lp  = fmaxf(__log2f(a * bs), LOG2_CLAMP);

    const float wbic = 0.2f / (float)(BB * CC * HWSZ);
    const float wcon = 0.8f / (float)(BB * CC * HWSZ);
    const float wpix = 1.0f / (float)(BB * HWSZ);
    const float ln2  = 0.69314718056f;

    float local = -(wbic * (Lb1 + Lb2) + wcon * (Lc1 + Lc2) + wpix * Lp) * ln2;

#pragma unroll
    for (int off = 32; off > 0; off >>= 1)
        local += __shfl_down(local, off, 64);

    const int lane = t & 63;
    const int wid  = t >> 6;
    if (lane == 0) wsum[wid] = local;
    __syncthreads();
    if (t == 0) {
        float s = 0.f;
#pragma unroll
        for (int i = 0; i < 8; ++i) s += wsum[i];
        atomicAdd(out, s);
    }
}

extern "C" void kernel_launch(void* const* d_in, const int* in_sizes, int n_in,
                              void* d_out, int out_size, void* d_ws, size_t ws_size,
                              hipStream_t stream) {
    const float* atts   = (const float*)d_in[0];
    const float* dets   = (const float*)d_in[1];
    const float* target = (const float*)d_in[2];
    const float* con    = (const float*)d_in[3];
    float* out = (float*)d_out;

    hipMemsetAsync(out, 0, sizeof(float), stream);

    bicon_loss_kernel<<<BB * HH, 512, 0, stream>>>(atts, dets, target, con, out);
}